// Round 12
// baseline (173.352 us; speedup 1.0000x reference)
//
#include <hip/hip_runtime.h>
#include <hip/hip_bf16.h>
#include <cstdint>
#include <cstddef>

#define BDIM 64
#define SDIM 512
#define HDIM 1024
#define MTOT (BDIM * SDIM)  // 32768

typedef __attribute__((ext_vector_type(8))) short short8;
typedef __attribute__((ext_vector_type(4))) float f32x4;

__device__ __forceinline__ unsigned int cvt2(float a, float b) {
  unsigned int r;
  asm("v_cvt_pk_bf16_f32 %0, %1, %2" : "=v"(r) : "v"(a), "v"(b));
  return r;
}

__device__ __forceinline__ void gld_lds16(const void* g, void* l) {
  __builtin_amdgcn_global_load_lds(
      (const __attribute__((address_space(1))) unsigned int*)g,
      (__attribute__((address_space(3))) unsigned int*)l, 16, 0, 0);
}

// tanh via hw exp2 + rcp: tanh(x) = 1 - 2/(e^{2x}+1). |err| ~1e-6, correct sat.
__device__ __forceinline__ float fast_tanh(float x) {
  const float e = __builtin_exp2f(x * 2.88539008f);  // 2*log2(e)
  return 1.0f - 2.0f * __builtin_amdgcn_rcpf(e + 1.0f);
}

// ---------- prep bodies (proven r2-r11) ----------
__device__ __forceinline__ void w2_body(const float* __restrict__ W,
                                        char* __restrict__ w2s, int bx, int tid) {
  const int n = bx * 2 + (tid >> 7);
  const int g = tid & 127;
  const int kt = g >> 3, gi = g & 7;
  const float* src = W + (size_t)n * 2048 + 1024 + g * 8;
  const float4 f0 = *reinterpret_cast<const float4*>(src);
  const float4 f1 = *reinterpret_cast<const float4*>(src + 4);
  uint4 u = make_uint4(cvt2(f0.x, f0.y), cvt2(f0.z, f0.w),
                       cvt2(f1.x, f1.y), cvt2(f1.z, f1.w));
  const int nblk = n >> 7, row = n & 127;
  const size_t off = ((size_t)(nblk * 16 + kt) * 128 + row) * 128 +
                     (size_t)(gi ^ (row & 7)) * 16;
  *reinterpret_cast<uint4*>(w2s + off) = u;
}

__device__ __forceinline__ void a_body(const float* __restrict__ hidden,
                                       const float* __restrict__ W,
                                       const float* __restrict__ bias,
                                       float* __restrict__ A, float* hl,
                                       int bx, int tid) {
  const int hc = bx & 3, b = bx >> 2;
  *reinterpret_cast<float4*>(&hl[tid * 4]) =
      *reinterpret_cast<const float4*>(hidden + (size_t)b * HDIM + tid * 4);
  __syncthreads();
  const int h = hc * 256 + tid;
  const float* wr = W + (size_t)h * 2048;
  float a0 = 0.f, a1 = 0.f, a2 = 0.f, a3 = 0.f;
  for (int k = 0; k < HDIM; k += 16) {
    const float4 w0 = *reinterpret_cast<const float4*>(wr + k);
    const float4 w1 = *reinterpret_cast<const float4*>(wr + k + 4);
    const float4 w2 = *reinterpret_cast<const float4*>(wr + k + 8);
    const float4 w3 = *reinterpret_cast<const float4*>(wr + k + 12);
    a0 += w0.x * hl[k]      + w0.y * hl[k + 1]  + w0.z * hl[k + 2]  + w0.w * hl[k + 3];
    a1 += w1.x * hl[k + 4]  + w1.y * hl[k + 5]  + w1.z * hl[k + 6]  + w1.w * hl[k + 7];
    a2 += w2.x * hl[k + 8]  + w2.y * hl[k + 9]  + w2.z * hl[k + 10] + w2.w * hl[k + 11];
    a3 += w3.x * hl[k + 12] + w3.y * hl[k + 13] + w3.z * hl[k + 14] + w3.w * hl[k + 15];
  }
  A[(size_t)b * HDIM + h] = bias[h] + ((a0 + a1) + (a2 + a3));
}

// ---- small prep: [0,512) W2 tiles | [512,768) A ----
__global__ __launch_bounds__(256) void prep_small_kernel(const float* __restrict__ W,
                                                         const float* __restrict__ hidden,
                                                         const float* __restrict__ bias,
                                                         char* __restrict__ w2s,
                                                         float* __restrict__ A) {
  __shared__ float hl[HDIM];
  const int bid = blockIdx.x;
  const int tid = threadIdx.x;
  if (bid < 512) w2_body(W, w2s, bid, tid);
  else a_body(hidden, W, bias, A, hl, bid - 512, tid);
}

// ---- main GEMM, n-split = 1 (A-traffic read ONCE):
//      block = 64 rows x 1024 cols, 16 waves of 64x64; BK=64; single-buffer
//      2-barrier loop. A: enc f32 -> LDS via gld_lds w/ pre-swizzled src
//      (slot = g ^ (row&7), 16 slots); cvt to bf16 in-reg after ds_read.
//      B: all 8 w2s tiles per kt via linear DMA (128 KB), L2-resident source.
//      Epilogue computes FINAL scores (no partials). ----
__global__ __launch_bounds__(1024, 4) void gemm_mega_kernel(const float* __restrict__ enc,
                                                            const char* __restrict__ w2s,
                                                            const float* __restrict__ A,
                                                            const float* __restrict__ v,
                                                            float* __restrict__ scores) {
  __shared__ __align__(16) char Af[16384];              // A kt-tile, f32, swizzled slots
  __shared__ __align__(16) char Bs[131072];             // 8 tiles x [128][64] ushort

  const int bid = blockIdx.x;       // 0..511  (one 64-row strip each)
  const int m0 = bid * 64;
  const int b = m0 >> 9;

  const int tid = threadIdx.x;
  const int w = tid >> 6, l = tid & 63;   // 16 waves; wave w owns n-band [w*64, w*64+64)
  const int lr = l & 15, lk = l >> 4;

  f32x4 acc[4][4];
#pragma unroll
  for (int i = 0; i < 4; ++i)
#pragma unroll
    for (int j = 0; j < 4; ++j) acc[i][j] = (f32x4){0.f, 0.f, 0.f, 0.f};

  // A staging source (per-lane pre-swizzled): LDS linear dest tid*16 ->
  // row = tid>>4, slot = tid&15, logical granule g = slot ^ (row&7) (low-3 XOR).
  const int arow = tid >> 4;
  const int aslot = tid & 15;
  const int ag = aslot ^ (arow & 7);
  const float* aSrc = enc + (size_t)(m0 + arow) * HDIM + ag * 4;
  char* aDst = Af + w * 1024;  // wave-uniform base; lane offset l*16 implicit

  // B: tile t (t = 0..7) at w2s + (t*16 + kt)*16384 ; dest Bs + t*16384.
  const char* bSrc0 = w2s + (size_t)w * 1024 + (size_t)(l) * 16;
  // per-wave uniform LDS chunk within each tile:
  const int bOfs = w * 1024;

  const int btile = w >> 1;            // this wave's B tile
  const int brow0 = (w & 1) * 64;      // row base inside the tile
  const char* Bh = Bs + btile * 16384;

  for (int kt = 0; kt < 16; ++kt) {
    __syncthreads();  // all waves done reading tile kt-1
    // --- stage A (1 gld_lds/thread) + B (8 gld_lds/thread) ---
    gld_lds16(aSrc + kt * 64, aDst);
#pragma unroll
    for (int t = 0; t < 8; ++t)
      gld_lds16(bSrc0 + ((size_t)t * 16 + kt) * 16384, Bs + t * 16384 + bOfs);
    __syncthreads();  // implicit vmcnt(0)+lgkmcnt(0): tile kt resident

#pragma unroll
    for (int ks = 0; ks < 2; ++ks) {
      short8 bfv[4];
#pragma unroll
      for (int j = 0; j < 4; ++j) {
        const int rb = brow0 + j * 16 + lr;
        const int gb = (ks * 4 + lk) ^ (rb & 7);
        bfv[j] = *reinterpret_cast<const short8*>(Bh + rb * 128 + gb * 16);
      }
#pragma unroll
      for (int f = 0; f < 4; ++f) {
        const int ra = f * 16 + lr;
        const int rx = ra & 7;
        const int gx = ks * 8 + 2 * lk;           // granules gx, gx+1
        const char* ap = Af + ra * 256;
        const float4 x = *reinterpret_cast<const float4*>(ap + (gx ^ rx) * 16);
        const float4 y = *reinterpret_cast<const float4*>(ap + ((gx + 1) ^ rx) * 16);
        uint4 u = make_uint4(cvt2(x.x, x.y), cvt2(x.z, x.w),
                             cvt2(y.x, y.y), cvt2(y.z, y.w));
        const short8 af = *reinterpret_cast<short8*>(&u);
#pragma unroll
        for (int j = 0; j < 4; ++j)
          acc[f][j] = __builtin_amdgcn_mfma_f32_16x16x32_bf16(af, bfv[j], acc[f][j], 0, 0, 0);
      }
    }
  }

  // ---- epilogue: score[m] = sum over ALL n of v[n]*tanh(C[m,n]+A[b,n]) ----
  float a_n[4], v_n[4];
#pragma unroll
  for (int j = 0; j < 4; ++j) {
    const int n = w * 64 + j * 16 + lr;
    a_n[j] = A[(size_t)b * HDIM + n];
    v_n[j] = v[n];
  }
  __syncthreads();                 // done with Af reads; reuse as reduction space
  float* red = reinterpret_cast<float*>(Af);  // [16][64]
#pragma unroll
  for (int f = 0; f < 4; ++f) {
#pragma unroll
    for (int r = 0; r < 4; ++r) {
      float s = 0.f;
#pragma unroll
      for (int j = 0; j < 4; ++j)
        s += v_n[j] * fast_tanh(acc[f][j][r] + a_n[j]);
      s += __shfl_xor(s, 1);
      s += __shfl_xor(s, 2);
      s += __shfl_xor(s, 4);
      s += __shfl_xor(s, 8);
      if (lr == 0) red[w * 64 + f * 16 + lk * 4 + r] = s;
    }
  }
  __syncthreads();
  if (tid < 64) {
    float sum = 0.f;
#pragma unroll
    for (int ww = 0; ww < 16; ++ww) sum += red[ww * 64 + tid];
    scores[(size_t)m0 + tid] = sum;
  }
}

// ---- softmax over s (512) per b; input = final scores ----
__global__ __launch_bounds__(512) void softmax_kernel(const float* __restrict__ scores,
                                                      float* __restrict__ wts) {
  const int b = blockIdx.x, s = threadIdx.x;
  const float sc = scores[(size_t)b * SDIM + s];
  float m = sc;
#pragma unroll
  for (int d = 1; d < 64; d <<= 1) m = fmaxf(m, __shfl_xor(m, d));
  __shared__ float redm[8], reds[8];
  if ((s & 63) == 0) redm[s >> 6] = m;
  __syncthreads();
  m = redm[0];
#pragma unroll
  for (int j = 1; j < 8; ++j) m = fmaxf(m, redm[j]);
  const float e = expf(sc - m);
  float sum = e;
#pragma unroll
  for (int d = 1; d < 64; d <<= 1) sum += __shfl_xor(sum, d);
  if ((s & 63) == 0) reds[s >> 6] = sum;
  __syncthreads();
  float tot = 0.f;
#pragma unroll
  for (int j = 0; j < 8; ++j) tot += reds[j];
  wts[(size_t)b * SDIM + s] = e / tot;
}

// ---- context[b,h] = sum_s w[b,s]*enc[b,s,h]; float2/lane ----
__global__ __launch_bounds__(256) void context_kernel(const float* __restrict__ enc,
                                                      const float* __restrict__ wts,
                                                      float* __restrict__ ctx) {
  const int hc = blockIdx.x;  // 0..1
  const int b  = blockIdx.y;  // 0..63
  const int t  = threadIdx.x;
  __shared__ float wl[SDIM];
  wl[t] = wts[(size_t)b * SDIM + t];
  wl[t + 256] = wts[(size_t)b * SDIM + 256 + t];
  __syncthreads();
  const int h = hc * 512 + t * 2;
  const float* e0 = enc + (size_t)b * SDIM * HDIM + h;
  float x0 = 0.f, y0 = 0.f, x1 = 0.f, y1 = 0.f;
  for (int s = 0; s < SDIM; s += 2) {
    const float2 v0 = *reinterpret_cast<const float2*>(e0 + (size_t)s * HDIM);
    const float2 v1 = *reinterpret_cast<const float2*>(e0 + (size_t)(s + 1) * HDIM);
    x0 += wl[s] * v0.x;     y0 += wl[s] * v0.y;
    x1 += wl[s + 1] * v1.x; y1 += wl[s + 1] * v1.y;
  }
  ctx[(size_t)b * HDIM + h]     = x0 + x1;
  ctx[(size_t)b * HDIM + h + 1] = y0 + y1;
}

extern "C" void kernel_launch(void* const* d_in, const int* in_sizes, int n_in,
                              void* d_out, int out_size, void* d_ws, size_t ws_size,
                              hipStream_t stream) {
  const float* hidden = (const float*)d_in[0];
  const float* enc    = (const float*)d_in[1];
  const float* W      = (const float*)d_in[2];
  const float* bias   = (const float*)d_in[3];
  const float* v      = (const float*)d_in[4];

  float* ctx = (float*)d_out;                // [64*1024] context
  float* wts = (float*)d_out + BDIM * HDIM;  // [64*512] attention weights

  char* ws = (char*)d_ws;
  char* w2s   = ws;                                                  // 2 MB swizzled W2 tiles
  float* A    = (float*)(ws + (size_t)2 * 1024 * 1024);              // 256 KB
  float* scr  = (float*)(ws + (size_t)2 * 1024 * 1024 + 256 * 1024); // 128 KB scores

  hipLaunchKernelGGL(prep_small_kernel, dim3(768), dim3(256), 0, stream,
                     W, hidden, bias, w2s, A);
  hipLaunchKernelGGL(gemm_mega_kernel, dim3(512), dim3(1024), 0, stream, enc, w2s, A, v, scr);
  hipLaunchKernelGGL(softmax_kernel, dim3(64), dim3(512), 0, stream, scr, wts);
  hipLaunchKernelGGL(context_kernel, dim3(2, 64), dim3(256), 0, stream, enc, wts, ctx);
}

// Round 13
// 138.756 us; speedup vs baseline: 1.2493x; 1.2493x over previous
//
#include <hip/hip_runtime.h>
#include <hip/hip_bf16.h>
#include <cstdint>
#include <cstddef>

#define BDIM 64
#define SDIM 512
#define HDIM 1024
#define MTOT (BDIM * SDIM)  // 32768

typedef __attribute__((ext_vector_type(8))) short short8;
typedef __attribute__((ext_vector_type(4))) float f32x4;

__device__ __forceinline__ unsigned int cvt2(float a, float b) {
  unsigned int r;
  asm("v_cvt_pk_bf16_f32 %0, %1, %2" : "=v"(r) : "v"(a), "v"(b));
  return r;
}

__device__ __forceinline__ void gld_lds16(const void* g, void* l) {
  __builtin_amdgcn_global_load_lds(
      (const __attribute__((address_space(1))) unsigned int*)g,
      (__attribute__((address_space(3))) unsigned int*)l, 16, 0, 0);
}

// tanh via hw exp2 + rcp: tanh(x) = 1 - 2/(e^{2x}+1). |err| ~1e-6, correct sat.
__device__ __forceinline__ float fast_tanh(float x) {
  const float e = __builtin_exp2f(x * 2.88539008f);  // 2*log2(e)
  return 1.0f - 2.0f * __builtin_amdgcn_rcpf(e + 1.0f);
}

// ---------- prep bodies (proven r2-r12) ----------
__device__ __forceinline__ void w2_body(const float* __restrict__ W,
                                        char* __restrict__ w2s, int bx, int tid) {
  const int n = bx * 2 + (tid >> 7);
  const int g = tid & 127;
  const int kt = g >> 3, gi = g & 7;
  const float* src = W + (size_t)n * 2048 + 1024 + g * 8;
  const float4 f0 = *reinterpret_cast<const float4*>(src);
  const float4 f1 = *reinterpret_cast<const float4*>(src + 4);
  uint4 u = make_uint4(cvt2(f0.x, f0.y), cvt2(f0.z, f0.w),
                       cvt2(f1.x, f1.y), cvt2(f1.z, f1.w));
  const int nblk = n >> 7, row = n & 127;
  const size_t off = ((size_t)(nblk * 16 + kt) * 128 + row) * 128 +
                     (size_t)(gi ^ (row & 7)) * 16;
  *reinterpret_cast<uint4*>(w2s + off) = u;
}

__device__ __forceinline__ void a_body(const float* __restrict__ hidden,
                                       const float* __restrict__ W,
                                       const float* __restrict__ bias,
                                       float* __restrict__ A, float* hl,
                                       int bx, int tid) {
  const int hc = bx & 3, b = bx >> 2;
  *reinterpret_cast<float4*>(&hl[tid * 4]) =
      *reinterpret_cast<const float4*>(hidden + (size_t)b * HDIM + tid * 4);
  __syncthreads();
  const int h = hc * 256 + tid;
  const float* wr = W + (size_t)h * 2048;
  float a0 = 0.f, a1 = 0.f, a2 = 0.f, a3 = 0.f;
  for (int k = 0; k < HDIM; k += 16) {
    const float4 w0 = *reinterpret_cast<const float4*>(wr + k);
    const float4 w1 = *reinterpret_cast<const float4*>(wr + k + 4);
    const float4 w2 = *reinterpret_cast<const float4*>(wr + k + 8);
    const float4 w3 = *reinterpret_cast<const float4*>(wr + k + 12);
    a0 += w0.x * hl[k]      + w0.y * hl[k + 1]  + w0.z * hl[k + 2]  + w0.w * hl[k + 3];
    a1 += w1.x * hl[k + 4]  + w1.y * hl[k + 5]  + w1.z * hl[k + 6]  + w1.w * hl[k + 7];
    a2 += w2.x * hl[k + 8]  + w2.y * hl[k + 9]  + w2.z * hl[k + 10] + w2.w * hl[k + 11];
    a3 += w3.x * hl[k + 12] + w3.y * hl[k + 13] + w3.z * hl[k + 14] + w3.w * hl[k + 15];
  }
  A[(size_t)b * HDIM + h] = bias[h] + ((a0 + a1) + (a2 + a3));
}

// ---- fused prep: [0,512) W2 tiles | [512,768) A ----
__global__ __launch_bounds__(256) void prep_small_kernel(const float* __restrict__ W,
                                                         const float* __restrict__ hidden,
                                                         const float* __restrict__ bias,
                                                         char* __restrict__ w2s,
                                                         float* __restrict__ A) {
  __shared__ float hl[HDIM];
  const int bid = blockIdx.x;
  const int tid = threadIdx.x;
  if (bid < 512) w2_body(W, w2s, bid, tid);
  else a_body(hidden, W, bias, A, hl, bid - 512, tid);
}

// ---- main GEMM (r6 champion, verbatim): 256x256 tile, 8 waves, BK=64, dbuf,
//      4 MFMA phases/K-tile; A reg-staged f32->bf16, B via global_load_lds ----
__global__ __launch_bounds__(512, 2) void gemm8f_kernel(const float* __restrict__ enc,
                                                        const char* __restrict__ w2s,
                                                        const float* __restrict__ A,
                                                        const float* __restrict__ v,
                                                        float* __restrict__ sp) {
  __shared__ __align__(16) unsigned short As[2][2][128][64];  // 64 KB
  __shared__ __align__(16) unsigned short Bs[2][2][128][64];  // 64 KB
  __shared__ float red4[4][256];                              // 4 KB

  const int bid = blockIdx.x;
  const int lg = (bid & 7) * 64 + (bid >> 3);  // XCD swizzle, 512 % 8 == 0
  const int nblk = lg & 3, mstrip = lg >> 2;
  const int m0 = mstrip * 256, n0 = nblk * 256;
  const int b = m0 >> 9;

  const int tid = threadIdx.x;
  const int w = tid >> 6, l = tid & 63;
  const int wm = w >> 2, wn = w & 3;  // 2 x 4 wave grid
  const int lr = l & 15, lk = l >> 4;

  f32x4 acc[8][4];
#pragma unroll
  for (int i = 0; i < 8; ++i)
#pragma unroll
    for (int j = 0; j < 4; ++j) acc[i][j] = (f32x4){0.f, 0.f, 0.f, 0.f};

  // A staging geometry: thread -> (row0 + i*64, granule g0); 4 iters = 256 rows
  const int row0 = tid >> 3, g0 = tid & 7;
  const float* encA = enc + (size_t)m0 * HDIM + g0 * 8;
  const char* bT0 = w2s + (size_t)((nblk * 2 + 0) * 16) * 16384;
  const char* bT1 = w2s + (size_t)((nblk * 2 + 1) * 16) * 16384;
  const int wbase = w * 1024;
  const int lofs = l * 16;

#define STAGE_B(srcp, dstp)                                                \
  do {                                                                     \
    gld_lds16((const char*)(srcp) + wbase + lofs, (char*)(dstp) + wbase);  \
    gld_lds16((const char*)(srcp) + 8192 + wbase + lofs,                   \
              (char*)(dstp) + 8192 + wbase);                               \
  } while (0)
#define LOAD_A(pfv, ii, ktv)                                                 \
  do {                                                                      \
    const float* s_ = encA + (size_t)(row0 + (ii) * 64) * HDIM + (ktv) * 64; \
    pfv[2 * (ii)]     = *reinterpret_cast<const float4*>(s_);               \
    pfv[2 * (ii) + 1] = *reinterpret_cast<const float4*>(s_ + 4);           \
  } while (0)

  float4 pf[8];
  LOAD_A(pf, 0, 0); LOAD_A(pf, 1, 0); LOAD_A(pf, 2, 0); LOAD_A(pf, 3, 0);
  STAGE_B(bT0, &Bs[0][0][0][0]);
  STAGE_B(bT1, &Bs[0][1][0][0]);

  const int gax = lr & 7;

  for (int kt = 0; kt < 16; ++kt) {
    const int cur = kt & 1, nxt = cur ^ 1;
    // convert + write A(kt) into As[cur] (swizzled slots)
#pragma unroll
    for (int i = 0; i < 4; ++i) {
      const int row = row0 + i * 64;
      uint4 u = make_uint4(cvt2(pf[2 * i].x, pf[2 * i].y),
                           cvt2(pf[2 * i].z, pf[2 * i].w),
                           cvt2(pf[2 * i + 1].x, pf[2 * i + 1].y),
                           cvt2(pf[2 * i + 1].z, pf[2 * i + 1].w));
      char* dst = reinterpret_cast<char*>(&As[cur][row >> 7][0][0]);
      *reinterpret_cast<uint4*>(dst + (row & 127) * 128 + ((g0 ^ (row & 7)) * 16)) = u;
    }
    __syncthreads();

    const bool pfb = (kt < 15);
    const char* Ah = (const char*)&As[cur][wm][0][0];
    const char* Bh = (const char*)&Bs[cur][wn >> 1][0][0];
    const int brow0 = (wn & 1) * 64;

    short8 af[4], bf[4];
#pragma unroll
    for (int ks = 0; ks < 2; ++ks) {
      const int gq = ((ks * 4 + lk) ^ gax) * 16;
#pragma unroll
      for (int mg = 0; mg < 2; ++mg) {
        if (pfb) {
          const int ph = ks * 2 + mg;
          if (ph == 0)      { LOAD_A(pf, 0, kt + 1); LOAD_A(pf, 1, kt + 1); }
          else if (ph == 1) { LOAD_A(pf, 2, kt + 1); LOAD_A(pf, 3, kt + 1); }
          else if (ph == 2) { STAGE_B(bT0 + (size_t)(kt + 1) * 16384, &Bs[nxt][0][0][0]); }
          else              { STAGE_B(bT1 + (size_t)(kt + 1) * 16384, &Bs[nxt][1][0][0]); }
        }
        if (mg == 0) {
#pragma unroll
          for (int f = 0; f < 4; ++f)
            bf[f] = *reinterpret_cast<const short8*>(
                Bh + (brow0 + f * 16 + lr) * 128 + gq);
        }
#pragma unroll
        for (int f = 0; f < 4; ++f)
          af[f] = *reinterpret_cast<const short8*>(
              Ah + ((mg * 4 + f) * 16 + lr) * 128 + gq);
        asm volatile("s_waitcnt lgkmcnt(0)" ::: "memory");
        __builtin_amdgcn_sched_barrier(0);
        __builtin_amdgcn_s_setprio(1);
#pragma unroll
        for (int fm = 0; fm < 4; ++fm)
#pragma unroll
          for (int fn = 0; fn < 4; ++fn)
            acc[mg * 4 + fm][fn] = __builtin_amdgcn_mfma_f32_16x16x32_bf16(
                af[fm], bf[fn], acc[mg * 4 + fm][fn], 0, 0, 0);
        __builtin_amdgcn_s_setprio(0);
      }
    }
  }
#undef STAGE_B
#undef LOAD_A

  // ---- epilogue: partial[m] = sum_n v[n] * tanh(C[m,n] + A[b,n]) ----
  float a_n[4], v_n[4];
#pragma unroll
  for (int fn = 0; fn < 4; ++fn) {
    const int n = wn * 64 + fn * 16 + lr;
    a_n[fn] = A[(size_t)b * HDIM + n0 + n];
    v_n[fn] = v[n0 + n];
  }
#pragma unroll
  for (int fm8 = 0; fm8 < 8; ++fm8) {
#pragma unroll
    for (int r = 0; r < 4; ++r) {
      float s = 0.f;
#pragma unroll
      for (int fn = 0; fn < 4; ++fn)
        s += v_n[fn] * fast_tanh(acc[fm8][fn][r] + a_n[fn]);
      s += __shfl_xor(s, 1);
      s += __shfl_xor(s, 2);
      s += __shfl_xor(s, 4);
      s += __shfl_xor(s, 8);
      if (lr == 0) red4[wn][wm * 128 + fm8 * 16 + lk * 4 + r] = s;
    }
  }
  __syncthreads();
  if (tid < 256) {
    const float ssum = red4[0][tid] + red4[1][tid] + red4[2][tid] + red4[3][tid];
    sp[(size_t)nblk * MTOT + m0 + tid] = ssum;
  }
}

// ---- softmax over s (512) per b; sums 4 partials ----
__global__ __launch_bounds__(512) void softmax4_kernel(const float* __restrict__ sp,
                                                       float* __restrict__ wts) {
  const int b = blockIdx.x, s = threadIdx.x;
  float sc = 0.f;
#pragma unroll
  for (int j = 0; j < 4; ++j) sc += sp[(size_t)j * MTOT + b * SDIM + s];
  float m = sc;
#pragma unroll
  for (int d = 1; d < 64; d <<= 1) m = fmaxf(m, __shfl_xor(m, d));
  __shared__ float redm[8], reds[8];
  if ((s & 63) == 0) redm[s >> 6] = m;
  __syncthreads();
  m = redm[0];
#pragma unroll
  for (int j = 1; j < 8; ++j) m = fmaxf(m, redm[j]);
  const float e = expf(sc - m);
  float sum = e;
#pragma unroll
  for (int d = 1; d < 64; d <<= 1) sum += __shfl_xor(sum, d);
  if ((s & 63) == 0) reds[s >> 6] = sum;
  __syncthreads();
  float tot = 0.f;
#pragma unroll
  for (int j = 0; j < 8; ++j) tot += reds[j];
  wts[(size_t)b * SDIM + s] = e / tot;
}

// ---- context[b,h] = sum_s w[b,s] * enc[b,s,h] (r6 version) ----
__global__ __launch_bounds__(256) void context_kernel(const float* __restrict__ enc,
                                                      const float* __restrict__ wts,
                                                      float* __restrict__ ctx) {
  const int hc = blockIdx.x;  // 0..3
  const int b  = blockIdx.y;  // 0..63
  const int t  = threadIdx.x;
  __shared__ float wl[SDIM];
  wl[t] = wts[(size_t)b * SDIM + t];
  wl[t + 256] = wts[(size_t)b * SDIM + 256 + t];
  __syncthreads();
  const int h = hc * 256 + t;
  const float* e0 = enc + (size_t)b * SDIM * HDIM + h;
  float acc0 = 0.f, acc1 = 0.f;
  for (int s = 0; s < SDIM; s += 2) {
    acc0 += wl[s] * e0[(size_t)s * HDIM];
    acc1 += wl[s + 1] * e0[(size_t)(s + 1) * HDIM];
  }
  ctx[(size_t)b * HDIM + h] = acc0 + acc1;
}

extern "C" void kernel_launch(void* const* d_in, const int* in_sizes, int n_in,
                              void* d_out, int out_size, void* d_ws, size_t ws_size,
                              hipStream_t stream) {
  const float* hidden = (const float*)d_in[0];
  const float* enc    = (const float*)d_in[1];
  const float* W      = (const float*)d_in[2];
  const float* bias   = (const float*)d_in[3];
  const float* v      = (const float*)d_in[4];

  float* ctx = (float*)d_out;                // [64*1024] context
  float* wts = (float*)d_out + BDIM * HDIM;  // [64*512] attention weights

  char* ws = (char*)d_ws;
  char* w2s = ws;                                                   // 2 MB swizzled W2 tiles
  float* A  = (float*)(ws + (size_t)2 * 1024 * 1024);               // 256 KB
  float* sp = (float*)(ws + (size_t)2 * 1024 * 1024 + 256 * 1024);  // 512 KB (4 partials)

  hipLaunchKernelGGL(prep_small_kernel, dim3(768), dim3(256), 0, stream,
                     W, hidden, bias, w2s, A);
  hipLaunchKernelGGL(gemm8f_kernel, dim3(512), dim3(512), 0, stream, enc, w2s, A, v, sp);
  hipLaunchKernelGGL(softmax4_kernel, dim3(64), dim3(512), 0, stream, sp, wts);
  hipLaunchKernelGGL(context_kernel, dim3(4, 64), dim3(256), 0, stream, enc, wts, ctx);
}